// Round 8
// baseline (283.163 us; speedup 1.0000x reference)
//
#include <hip/hip_runtime.h>
#include <math.h>

// SelfAttentionLayer B=4, N=2048, D=E=1024, fp32 in/out.
// out[b,j,e] = sum_i softmax_i(q_i . k_j / 32) * v[b,i,e]
// R8: Q/K projections eliminated: scores = x (Wq Wk^T/32) x^T.
//     M' = (Wk Wq^T)/32 precomputed (2.1 GF) inside prep launch;
//     y = x M'^T fused with V projection; scores = y x^T with exp epilogue.
//     105 GF total (was 120), QK intermediate (32MB wr + 64MB rd) removed.
//
// ws (ushort): xb[8M] Wvt[1M] Bm[1M] y[8M] Vtb[8M] Pb[16M] l[8192 f32].

typedef __bf16 bf16x8 __attribute__((ext_vector_type(8)));
typedef float f32x4 __attribute__((ext_vector_type(4)));

static __device__ __forceinline__ unsigned short f2bf(float f) {
    unsigned u = __float_as_uint(f);
    u += 0x7fff + ((u >> 16) & 1);   // round-to-nearest-even
    return (unsigned short)(u >> 16);
}

#define GLDS16(gptr, lptr)                                                            \
    __builtin_amdgcn_global_load_lds(                                                 \
        (const __attribute__((address_space(1))) void*)(gptr),                        \
        (__attribute__((address_space(3))) void*)(lptr), 16, 0, 0)

// ---------------- Kernel A: prep + M' GEMM ----------------
// blocks [0,8192): convert x -> xb (bf16)
// blocks [8192,9216): transpose-convert Wv -> Wvt
// block 9216: zero l
// blocks [9217,9281): M'[m,n] = (sum_e Wk[m,e]*Wq[n,e])/32, fp32 in, bf16 out.
//   128x128 tiles (8x8 grid), BK=32, VGPR-staged fp32->bf16 into swizzled LDS.
__global__ __launch_bounds__(256) void prep_m(
    const float* __restrict__ x,
    const float* __restrict__ Wq, const float* __restrict__ Wk,
    const float* __restrict__ Wv,
    unsigned short* __restrict__ xb, unsigned short* __restrict__ Wvt,
    unsigned short* __restrict__ Bm, float* __restrict__ l)
{
    __shared__ unsigned short smem[2 * 128 * 32];   // 16 KB; aliased by transpose
    const int b = blockIdx.x;
    const int tid = threadIdx.x;

    if (b < 8192) {
        int i = b * 256 + tid;
        float4 v = ((const float4*)x)[i];
        ushort4 o;
        o.x = f2bf(v.x); o.y = f2bf(v.y); o.z = f2bf(v.z); o.w = f2bf(v.w);
        ((ushort4*)xb)[i] = o;
        return;
    }
    if (b < 9216) {
        float(*t)[33] = (float(*)[33])smem;
        int tix = b - 8192;
        const int bx = (tix & 31) * 32;
        const int by = (tix >> 5) * 32;
        const int tx = tid & 31;
        const int ty = (tid >> 5) * 4;
#pragma unroll
        for (int j = 0; j < 4; j++)
            t[ty + j][tx] = Wv[(long)(by + ty + j) * 1024 + bx + tx];
        __syncthreads();
#pragma unroll
        for (int j = 0; j < 4; j++)
            Wvt[(long)(bx + ty + j) * 1024 + by + tx] = f2bf(t[tx][ty + j]);
        return;
    }
    if (b == 9216) {
        float4 z = {0.f, 0.f, 0.f, 0.f};
#pragma unroll
        for (int i = 0; i < 8; i++)
            ((float4*)l)[tid * 8 + i] = z;
        return;
    }

    // ---- M' GEMM ----
    unsigned short* As = smem;              // 128x32
    unsigned short* Bs = smem + 128 * 32;   // 128x32
    const int g = b - 9217;
    const long gm0 = (long)(g >> 3) * 128;
    const long gn0 = (long)(g & 7) * 128;

    const int wave = tid >> 6;
    const int lane = tid & 63;
    const int wm   = (wave & 1) * 64;
    const int wn   = (wave >> 1) * 64;
    const int fr   = lane & 15;
    const int quad = lane >> 4;
    const int swf  = (fr >> 1) & 3;

    const int sr   = tid >> 1;             // staging row 0..127
    const int cseg = (tid & 1) * 16;       // col segment base
    const int swr  = (sr >> 1) & 3;

    f32x4 acc[4][4];
#pragma unroll
    for (int i = 0; i < 4; i++)
#pragma unroll
        for (int j = 0; j < 4; j++) acc[i][j] = f32x4{0.f, 0.f, 0.f, 0.f};

    for (int k0 = 0; k0 < 1024; k0 += 32) {
#pragma unroll
        for (int u = 0; u < 4; u++) {
            const int c = cseg + u * 4;
            const int sl = sr * 32 + (((c >> 3) ^ swr) * 8) + (c & 4);
            float4 a = *(const float4*)&Wk[(gm0 + sr) * 1024 + k0 + c];
            ushort4 oa;
            oa.x = f2bf(a.x); oa.y = f2bf(a.y); oa.z = f2bf(a.z); oa.w = f2bf(a.w);
            *(ushort4*)&As[sl] = oa;
            float4 bv = *(const float4*)&Wq[(gn0 + sr) * 1024 + k0 + c];
            ushort4 ob;
            ob.x = f2bf(bv.x); ob.y = f2bf(bv.y); ob.z = f2bf(bv.z); ob.w = f2bf(bv.w);
            *(ushort4*)&Bs[sl] = ob;
        }
        __syncthreads();

        const int qs = (quad ^ swf) * 8;
        bf16x8 af[4], bf[4];
#pragma unroll
        for (int i = 0; i < 4; i++)
            af[i] = *(const bf16x8*)&As[(wm + i * 16 + fr) * 32 + qs];
#pragma unroll
        for (int j = 0; j < 4; j++)
            bf[j] = *(const bf16x8*)&Bs[(wn + j * 16 + fr) * 32 + qs];
#pragma unroll
        for (int i = 0; i < 4; i++)
#pragma unroll
            for (int j = 0; j < 4; j++)
                acc[i][j] = __builtin_amdgcn_mfma_f32_16x16x32_bf16(
                    af[i], bf[j], acc[i][j], 0, 0, 0);
        __syncthreads();
    }

    const long crow0 = gm0 + wm + quad * 4;
#pragma unroll
    for (int i = 0; i < 4; i++) {
        const long rb = crow0 + i * 16;
#pragma unroll
        for (int j = 0; j < 4; j++) {
            const long cb = gn0 + wn + j * 16 + fr;
#pragma unroll
            for (int rr = 0; rr < 4; rr++)
                Bm[(rb + rr) * 1024L + cb] = f2bf(acc[i][j][rr] * 0.03125f);
        }
    }
}

// ---------------- Kernel B: y + Vt fused GEMM ----------------
// A = xb [8192x1024]. n<1024: B=Bm -> y[m*1024+n] (y = x M'^T, includes /32).
// n>=1024: B=Wvt -> Vt[(n-1024)*8192+m] (8B contiguous stores).
__global__ __launch_bounds__(256) void gemm_yv(
    const unsigned short* __restrict__ A, const unsigned short* __restrict__ Bm,
    const unsigned short* __restrict__ Wvt,
    unsigned short* __restrict__ y, unsigned short* __restrict__ Vt)
{
    __shared__ unsigned short As[128 * 64];
    __shared__ unsigned short Bs[128 * 64];

    const int tid  = threadIdx.x;
    const int wave = tid >> 6;
    const int lane = tid & 63;
    const long gm0 = (long)blockIdx.y * 128;
    const long gn0 = (long)blockIdx.x * 128;
    const bool isV = gn0 >= 1024;
    const long nb  = isV ? gn0 - 1024 : gn0;
    const unsigned short* Bbase = isV ? Wvt : Bm;

    const int r = lane >> 3;
    const int s = lane & 7;
    const int cg = (s ^ r) * 8;
    const unsigned short* ap = A + (gm0 + wave * 32 + r) * 1024L + cg;
    const unsigned short* bp = Bbase + (nb + wave * 32 + r) * 1024L + cg;
    unsigned short* asl = &As[wave * 2048];
    unsigned short* bsl = &Bs[wave * 2048];

    const int wm   = (wave & 1) * 64;
    const int wn   = (wave >> 1) * 64;
    const int fr   = lane & 15;
    const int quad = lane >> 4;
    const int sw   = fr & 7;

    f32x4 acc[4][4];
#pragma unroll
    for (int i = 0; i < 4; i++)
#pragma unroll
        for (int j = 0; j < 4; j++) acc[i][j] = f32x4{0.f, 0.f, 0.f, 0.f};

    for (int k0 = 0; k0 < 1024; k0 += 64) {
        GLDS16(ap, asl);
        GLDS16(ap + 8 * 1024L, asl + 512);
        GLDS16(ap + 16 * 1024L, asl + 1024);
        GLDS16(ap + 24 * 1024L, asl + 1536);
        GLDS16(bp, bsl);
        GLDS16(bp + 8 * 1024L, bsl + 512);
        GLDS16(bp + 16 * 1024L, bsl + 1024);
        GLDS16(bp + 24 * 1024L, bsl + 1536);
        ap += 64;
        bp += 64;
        __syncthreads();

#pragma unroll
        for (int t = 0; t < 2; t++) {
            const int qs = ((t * 4 + quad) ^ sw) * 8;
            bf16x8 af[4], bf[4];
#pragma unroll
            for (int i = 0; i < 4; i++)
                af[i] = *(const bf16x8*)&As[(wm + i * 16 + fr) * 64 + qs];
#pragma unroll
            for (int j = 0; j < 4; j++)
                bf[j] = *(const bf16x8*)&Bs[(wn + j * 16 + fr) * 64 + qs];
#pragma unroll
            for (int i = 0; i < 4; i++)
#pragma unroll
                for (int j = 0; j < 4; j++)
                    acc[i][j] = __builtin_amdgcn_mfma_f32_16x16x32_bf16(
                        af[i], bf[j], acc[i][j], 0, 0, 0);
        }
        __syncthreads();
    }

    const long crow0 = gm0 + wm + quad * 4;
    if (!isV) {
#pragma unroll
        for (int i = 0; i < 4; i++) {
            const long rb = crow0 + i * 16;
#pragma unroll
            for (int j = 0; j < 4; j++) {
                const long cb = nb + wn + j * 16 + fr;
#pragma unroll
                for (int rr = 0; rr < 4; rr++)
                    y[(rb + rr) * 1024L + cb] = f2bf(acc[i][j][rr]);
            }
        }
    } else {
#pragma unroll
        for (int i = 0; i < 4; i++) {
            const long rb = crow0 + i * 16;
#pragma unroll
            for (int j = 0; j < 4; j++) {
                const long ce = nb + wn + j * 16 + fr;
                ushort4 o;
                o.x = f2bf(acc[i][j][0]);
                o.y = f2bf(acc[i][j][1]);
                o.z = f2bf(acc[i][j][2]);
                o.w = f2bf(acc[i][j][3]);
                *(ushort4*)&Vt[ce * 8192L + rb] = o;
            }
        }
    }
}

// ---------------- Kernel C: scores P'[j,i] = exp(y_i . x_j), + row sums ----
// A = xb_b (rows j), B = y_b (rows i). K=1024. scale already folded into M'.
__global__ __launch_bounds__(256) void gemm_scores(
    const unsigned short* __restrict__ xb, const unsigned short* __restrict__ y,
    unsigned short* __restrict__ P, float* __restrict__ l)
{
    __shared__ unsigned short As[128 * 64];
    __shared__ unsigned short Bs[128 * 64];

    const int tid  = threadIdx.x;
    const int wave = tid >> 6;
    const int lane = tid & 63;
    const int bz   = blockIdx.z;
    const long gm0 = (long)blockIdx.y * 128;   // j
    const long gn0 = (long)blockIdx.x * 128;   // i

    const unsigned short* Ab = xb + (long)bz * 2048 * 1024;
    const unsigned short* Bb = y + (long)bz * 2048 * 1024;

    const int r = lane >> 3;
    const int s = lane & 7;
    const int cg = (s ^ r) * 8;
    const unsigned short* ap = Ab + (gm0 + wave * 32 + r) * 1024L + cg;
    const unsigned short* bp = Bb + (gn0 + wave * 32 + r) * 1024L + cg;
    unsigned short* asl = &As[wave * 2048];
    unsigned short* bsl = &Bs[wave * 2048];

    const int wm   = (wave & 1) * 64;
    const int wn   = (wave >> 1) * 64;
    const int fr   = lane & 15;
    const int quad = lane >> 4;
    const int sw   = fr & 7;

    f32x4 acc[4][4];
#pragma unroll
    for (int i = 0; i < 4; i++)
#pragma unroll
        for (int j = 0; j < 4; j++) acc[i][j] = f32x4{0.f, 0.f, 0.f, 0.f};

    for (int k0 = 0; k0 < 1024; k0 += 64) {
        GLDS16(ap, asl);
        GLDS16(ap + 8 * 1024L, asl + 512);
        GLDS16(ap + 16 * 1024L, asl + 1024);
        GLDS16(ap + 24 * 1024L, asl + 1536);
        GLDS16(bp, bsl);
        GLDS16(bp + 8 * 1024L, bsl + 512);
        GLDS16(bp + 16 * 1024L, bsl + 1024);
        GLDS16(bp + 24 * 1024L, bsl + 1536);
        ap += 64;
        bp += 64;
        __syncthreads();

#pragma unroll
        for (int t = 0; t < 2; t++) {
            const int qs = ((t * 4 + quad) ^ sw) * 8;
            bf16x8 af[4], bf[4];
#pragma unroll
            for (int i = 0; i < 4; i++)
                af[i] = *(const bf16x8*)&As[(wm + i * 16 + fr) * 64 + qs];
#pragma unroll
            for (int j = 0; j < 4; j++)
                bf[j] = *(const bf16x8*)&Bs[(wn + j * 16 + fr) * 64 + qs];
#pragma unroll
            for (int i = 0; i < 4; i++)
#pragma unroll
                for (int j = 0; j < 4; j++)
                    acc[i][j] = __builtin_amdgcn_mfma_f32_16x16x32_bf16(
                        af[i], bf[j], acc[i][j], 0, 0, 0);
        }
        __syncthreads();
    }

    unsigned short* Pb = P + (long)bz * 2048 * 2048;
    float* lb = l + (long)bz * 2048;
    const long crow0 = gm0 + wm + quad * 4;
#pragma unroll
    for (int i = 0; i < 4; i++) {
        const long rb = crow0 + i * 16;
        float rs[4] = {0.f, 0.f, 0.f, 0.f};
#pragma unroll
        for (int j = 0; j < 4; j++) {
            const long cb = gn0 + wn + j * 16 + fr;
#pragma unroll
            for (int rr = 0; rr < 4; rr++) {
                float e = __expf(acc[i][j][rr]);
                rs[rr] += e;
                Pb[(rb + rr) * 2048L + cb] = f2bf(e);
            }
        }
#pragma unroll
        for (int rr = 0; rr < 4; rr++) {
#pragma unroll
            for (int m = 8; m > 0; m >>= 1) rs[rr] += __shfl_xor(rs[rr], m, 16);
        }
        if (fr == 0) {
#pragma unroll
            for (int rr = 0; rr < 4; rr++)
                atomicAdd(&lb[rb + rr], rs[rr]);
        }
    }
}

// ---------------- Kernel D: PV, 64x128 tiles, fp32 out, /l[row] ----------------
__global__ __launch_bounds__(256) void gemm_pv(
    const unsigned short* __restrict__ P, const unsigned short* __restrict__ Vt,
    const float* __restrict__ l, float* __restrict__ out)
{
    __shared__ unsigned short As[64 * 64];
    __shared__ unsigned short Bs[128 * 64];

    const int tid  = threadIdx.x;
    const int wave = tid >> 6;
    const int lane = tid & 63;
    const int bz   = blockIdx.z;
    const long gm0 = (long)blockIdx.y * 64;    // j
    const long gn0 = (long)blockIdx.x * 128;   // e

    const unsigned short* Ab = P + (long)bz * 2048 * 2048;
    const unsigned short* Bb = Vt + (long)bz * 2048;

    const int r = lane >> 3;
    const int s = lane & 7;
    const int cg = (s ^ r) * 8;
    const unsigned short* ap = Ab + (gm0 + wave * 16 + r) * 2048L + cg;
    const unsigned short* bp = Bb + (gn0 + wave * 32 + r) * 8192L + cg;
    unsigned short* asl = &As[wave * 1024];
    unsigned short* bsl = &Bs[wave * 2048];

    const int fr   = lane & 15;
    const int quad = lane >> 4;
    const int sw   = fr & 7;

    f32x4 acc[4][2];
#pragma unroll
    for (int i = 0; i < 4; i++)
#pragma unroll
        for (int j = 0; j < 2; j++) acc[i][j] = f32x4{0.f, 0.f, 0.f, 0.f};

    for (int k0 = 0; k0 < 2048; k0 += 64) {
        GLDS16(ap, asl);
        GLDS16(ap + 8 * 2048L, asl + 512);
        GLDS16(bp, bsl);
        GLDS16(bp + 8 * 8192L, bsl + 512);
        GLDS16(bp + 16 * 8192L, bsl + 1024);
        GLDS16(bp + 24 * 8192L, bsl + 1536);
        ap += 64;
        bp += 64;
        __syncthreads();

#pragma unroll
        for (int t = 0; t < 2; t++) {
            const int qs = ((t * 4 + quad) ^ sw) * 8;
            bf16x8 af[4], bf[2];
#pragma unroll
            for (int i = 0; i < 4; i++)
                af[i] = *(const bf16x8*)&As[(i * 16 + fr) * 64 + qs];
#pragma unroll
            for (int j = 0; j < 2; j++)
                bf[j] = *(const bf16x8*)&Bs[(wave * 32 + j * 16 + fr) * 64 + qs];
#pragma unroll
            for (int i = 0; i < 4; i++)
#pragma unroll
                for (int j = 0; j < 2; j++)
                    acc[i][j] = __builtin_amdgcn_mfma_f32_16x16x32_bf16(
                        af[i], bf[j], acc[i][j], 0, 0, 0);
        }
        __syncthreads();
    }

    float* Ob = out + (long)bz * 2048 * 1024;
    const float* lb = l + (long)bz * 2048;
    const long crow0 = gm0 + quad * 4;
#pragma unroll
    for (int i = 0; i < 4; i++) {
        const long rb = crow0 + i * 16;
        float inv[4];
#pragma unroll
        for (int rr = 0; rr < 4; rr++) inv[rr] = 1.0f / lb[rb + rr];
#pragma unroll
        for (int j = 0; j < 2; j++) {
            const long cb = gn0 + wave * 32 + j * 16 + fr;
#pragma unroll
            for (int rr = 0; rr < 4; rr++)
                Ob[(rb + rr) * 1024L + cb] = acc[i][j][rr] * inv[rr];
        }
    }
}

extern "C" void kernel_launch(void* const* d_in, const int* in_sizes, int n_in,
                              void* d_out, int out_size, void* d_ws,
                              size_t ws_size, hipStream_t stream)
{
    const float* x  = (const float*)d_in[0];
    const float* Wq = (const float*)d_in[1];
    const float* Wk = (const float*)d_in[2];
    const float* Wv = (const float*)d_in[3];
    float* out = (float*)d_out;

    const long M1 = 1024 * 1024;
    unsigned short* u    = (unsigned short*)d_ws;
    unsigned short* xb   = u;                  // 8M
    unsigned short* Wvt  = u + 8 * M1;         // 1M
    unsigned short* Bm   = Wvt + M1;           // 1M  M' = (Wk Wq^T)/32
    unsigned short* yb   = Bm + M1;            // 8M  [8192 x 1024]
    unsigned short* Vtb  = yb + 8 * M1;        // 8M  [1024 x 8192]
    unsigned short* Pb   = Vtb + 8 * M1;       // 16M [4 x 2048 x 2048]
    float* l             = (float*)(Pb + 16 * M1);  // 8192 f32

    dim3 blk(256);

    // prep (x convert, Wv transpose, zero l) + M' GEMM, one launch
    prep_m<<<dim3(8192 + 1024 + 1 + 64), blk, 0, stream>>>(
        x, Wq, Wk, Wv, xb, Wvt, Bm, l);

    // y = x M'^T (scale folded) fused with Vt = (x Wv)^T
    gemm_yv<<<dim3(16, 64), blk, 0, stream>>>(xb, Bm, Wvt, yb, Vtb);

    // P'[j,i] = exp(y_i . x_j) bf16, + row sums l
    gemm_scores<<<dim3(16, 16, 4), blk, 0, stream>>>(xb, yb, Pb, l);

    // out = (P' @ V) / l
    gemm_pv<<<dim3(8, 32, 4), blk, 0, stream>>>(Pb, Vtb, l, out);
}

// Round 9
// 246.031 us; speedup vs baseline: 1.1509x; 1.1509x over previous
//
#include <hip/hip_runtime.h>
#include <math.h>

// SelfAttentionLayer B=4, N=2048, D=E=1024, fp32 in/out.
// out[b,j,e] = sum_i softmax_i(q_i . k_j / 32) * v[b,i,e]
// R9: revert R8's M' factorization (prep tail was latency-bound, ate the
//     saving). R7 pipeline + PV back to 128x128 tiles (R6's 64x128 doubled
//     Vt re-reads: FETCH 139MB, 64.6us, fetch-bound). 4 launches.
//
// ws (ushort): xb[8M] Wqkvt[3M] QKb[16M] Vtb[8M] Pb[16M] l[8192 f32].

typedef __bf16 bf16x8 __attribute__((ext_vector_type(8)));
typedef float f32x4 __attribute__((ext_vector_type(4)));

static __device__ __forceinline__ unsigned short f2bf(float f) {
    unsigned u = __float_as_uint(f);
    u += 0x7fff + ((u >> 16) & 1);   // round-to-nearest-even
    return (unsigned short)(u >> 16);
}

#define GLDS16(gptr, lptr)                                                            \
    __builtin_amdgcn_global_load_lds(                                                 \
        (const __attribute__((address_space(1))) void*)(gptr),                        \
        (__attribute__((address_space(3))) void*)(lptr), 16, 0, 0)

// ---------------- scores GEMM: P'[j,i] = exp((K_j . Q_i)/32), + row sums ----
__global__ __launch_bounds__(256) void gemm_scores(
    const unsigned short* __restrict__ QKb, unsigned short* __restrict__ P,
    float* __restrict__ l)
{
    __shared__ unsigned short As[128 * 64];
    __shared__ unsigned short Bs[128 * 64];

    const int tid  = threadIdx.x;
    const int wave = tid >> 6;
    const int lane = tid & 63;
    const int bz   = blockIdx.z;
    const long gm0 = (long)blockIdx.y * 128;   // j
    const long gn0 = (long)blockIdx.x * 128;   // i

    const unsigned short* Ab = QKb + (long)bz * 2048 * 2048 + 1024;  // K cols
    const unsigned short* Bb = QKb + (long)bz * 2048 * 2048;         // Q cols

    const int r = lane >> 3;
    const int s = lane & 7;
    const int cg = (s ^ r) * 8;
    const unsigned short* ap = Ab + (gm0 + wave * 32 + r) * 2048L + cg;
    const unsigned short* bp = Bb + (gn0 + wave * 32 + r) * 2048L + cg;
    unsigned short* asl = &As[wave * 2048];
    unsigned short* bsl = &Bs[wave * 2048];

    const int wm   = (wave & 1) * 64;
    const int wn   = (wave >> 1) * 64;
    const int fr   = lane & 15;
    const int quad = lane >> 4;
    const int sw   = fr & 7;

    f32x4 acc[4][4];
#pragma unroll
    for (int i = 0; i < 4; i++)
#pragma unroll
        for (int j = 0; j < 4; j++) acc[i][j] = f32x4{0.f, 0.f, 0.f, 0.f};

    for (int k0 = 0; k0 < 1024; k0 += 64) {
        GLDS16(ap, asl);
        GLDS16(ap + 8 * 2048L, asl + 512);
        GLDS16(ap + 16 * 2048L, asl + 1024);
        GLDS16(ap + 24 * 2048L, asl + 1536);
        GLDS16(bp, bsl);
        GLDS16(bp + 8 * 2048L, bsl + 512);
        GLDS16(bp + 16 * 2048L, bsl + 1024);
        GLDS16(bp + 24 * 2048L, bsl + 1536);
        ap += 64;
        bp += 64;
        __syncthreads();

#pragma unroll
        for (int t = 0; t < 2; t++) {
            const int qs = ((t * 4 + quad) ^ sw) * 8;
            bf16x8 af[4], bf[4];
#pragma unroll
            for (int i = 0; i < 4; i++)
                af[i] = *(const bf16x8*)&As[(wm + i * 16 + fr) * 64 + qs];
#pragma unroll
            for (int j = 0; j < 4; j++)
                bf[j] = *(const bf16x8*)&Bs[(wn + j * 16 + fr) * 64 + qs];
#pragma unroll
            for (int i = 0; i < 4; i++)
#pragma unroll
                for (int j = 0; j < 4; j++)
                    acc[i][j] = __builtin_amdgcn_mfma_f32_16x16x32_bf16(
                        af[i], bf[j], acc[i][j], 0, 0, 0);
        }
        __syncthreads();
    }

    unsigned short* Pb = P + (long)bz * 2048 * 2048;
    float* lb = l + (long)bz * 2048;
    const long crow0 = gm0 + wm + quad * 4;
    const float scale = 1.0f / 32.0f;
#pragma unroll
    for (int i = 0; i < 4; i++) {
        const long rb = crow0 + i * 16;
        float rs[4] = {0.f, 0.f, 0.f, 0.f};
#pragma unroll
        for (int j = 0; j < 4; j++) {
            const long cb = gn0 + wn + j * 16 + fr;
#pragma unroll
            for (int rr = 0; rr < 4; rr++) {
                float e = __expf(acc[i][j][rr] * scale);
                rs[rr] += e;
                Pb[(rb + rr) * 2048L + cb] = f2bf(e);
            }
        }
#pragma unroll
        for (int rr = 0; rr < 4; rr++) {
#pragma unroll
            for (int m = 8; m > 0; m >>= 1) rs[rr] += __shfl_xor(rs[rr], m, 16);
        }
        if (fr == 0) {
#pragma unroll
            for (int rr = 0; rr < 4; rr++)
                atomicAdd(&lb[rb + rr], rs[rr]);
        }
    }
}

// ---------------- QKV fused GEMM ----------------
// A = xb [8192x1024]; B = Wqkvt [3072x1024] (Wq^T|Wk^T|Wv^T).
// n < 2048  -> QK[m*2048 + n] (bf16);  n >= 2048 -> Vt[(n-2048)*8192 + m]
__global__ __launch_bounds__(256) void gemm_qkv(
    const unsigned short* __restrict__ A, const unsigned short* __restrict__ B,
    unsigned short* __restrict__ QK, unsigned short* __restrict__ Vt)
{
    __shared__ unsigned short As[128 * 64];
    __shared__ unsigned short Bs[128 * 64];

    const int tid  = threadIdx.x;
    const int wave = tid >> 6;
    const int lane = tid & 63;
    const long gm0 = (long)blockIdx.y * 128;
    const long gn0 = (long)blockIdx.x * 128;

    const int r = lane >> 3;
    const int s = lane & 7;
    const int cg = (s ^ r) * 8;
    const unsigned short* ap = A + (gm0 + wave * 32 + r) * 1024L + cg;
    const unsigned short* bp = B + (gn0 + wave * 32 + r) * 1024L + cg;
    unsigned short* asl = &As[wave * 2048];
    unsigned short* bsl = &Bs[wave * 2048];

    const int wm   = (wave & 1) * 64;
    const int wn   = (wave >> 1) * 64;
    const int fr   = lane & 15;
    const int quad = lane >> 4;
    const int sw   = fr & 7;

    f32x4 acc[4][4];
#pragma unroll
    for (int i = 0; i < 4; i++)
#pragma unroll
        for (int j = 0; j < 4; j++) acc[i][j] = f32x4{0.f, 0.f, 0.f, 0.f};

    for (int k0 = 0; k0 < 1024; k0 += 64) {
        GLDS16(ap, asl);
        GLDS16(ap + 8 * 1024L, asl + 512);
        GLDS16(ap + 16 * 1024L, asl + 1024);
        GLDS16(ap + 24 * 1024L, asl + 1536);
        GLDS16(bp, bsl);
        GLDS16(bp + 8 * 1024L, bsl + 512);
        GLDS16(bp + 16 * 1024L, bsl + 1024);
        GLDS16(bp + 24 * 1024L, bsl + 1536);
        ap += 64;
        bp += 64;
        __syncthreads();

#pragma unroll
        for (int t = 0; t < 2; t++) {
            const int qs = ((t * 4 + quad) ^ sw) * 8;
            bf16x8 af[4], bf[4];
#pragma unroll
            for (int i = 0; i < 4; i++)
                af[i] = *(const bf16x8*)&As[(wm + i * 16 + fr) * 64 + qs];
#pragma unroll
            for (int j = 0; j < 4; j++)
                bf[j] = *(const bf16x8*)&Bs[(wn + j * 16 + fr) * 64 + qs];
#pragma unroll
            for (int i = 0; i < 4; i++)
#pragma unroll
                for (int j = 0; j < 4; j++)
                    acc[i][j] = __builtin_amdgcn_mfma_f32_16x16x32_bf16(
                        af[i], bf[j], acc[i][j], 0, 0, 0);
        }
        __syncthreads();
    }

    const long crow0 = gm0 + wm + quad * 4;
    if (gn0 < 2048) {
#pragma unroll
        for (int i = 0; i < 4; i++) {
            const long rb = crow0 + i * 16;
#pragma unroll
            for (int j = 0; j < 4; j++) {
                const long cb = gn0 + wn + j * 16 + fr;
#pragma unroll
                for (int rr = 0; rr < 4; rr++)
                    QK[(rb + rr) * 2048L + cb] = f2bf(acc[i][j][rr]);
            }
        }
    } else {
#pragma unroll
        for (int i = 0; i < 4; i++) {
            const long rb = crow0 + i * 16;
#pragma unroll
            for (int j = 0; j < 4; j++) {
                const long ce = gn0 - 2048 + wn + j * 16 + fr;
                ushort4 o;
                o.x = f2bf(acc[i][j][0]);
                o.y = f2bf(acc[i][j][1]);
                o.z = f2bf(acc[i][j][2]);
                o.w = f2bf(acc[i][j][3]);
                *(ushort4*)&Vt[ce * 8192L + rb] = o;
            }
        }
    }
}

// ---------------- PV GEMM: 128x128 tiles, fp32 out, /l[row] ----------------
// out_b[j,e] = (sum_i P'_b[j,i] * Vt[e, b*2048+i]) / l[b][j]
// grid (8 e-tiles, 16 j-tiles, 4 batches). Same-e blocks are 8 apart in
// dispatch order -> same XCD -> Vt tile stays L2-resident.
__global__ __launch_bounds__(256) void gemm_pv(
    const unsigned short* __restrict__ P, const unsigned short* __restrict__ Vt,
    const float* __restrict__ l, float* __restrict__ out)
{
    __shared__ unsigned short As[128 * 64];
    __shared__ unsigned short Bs[128 * 64];

    const int tid  = threadIdx.x;
    const int wave = tid >> 6;
    const int lane = tid & 63;
    const int bz   = blockIdx.z;
    const long gm0 = (long)blockIdx.y * 128;   // j
    const long gn0 = (long)blockIdx.x * 128;   // e

    const unsigned short* Ab = P + (long)bz * 2048 * 2048;
    const unsigned short* Bb = Vt + (long)bz * 2048;

    const int r = lane >> 3;
    const int s = lane & 7;
    const int cg = (s ^ r) * 8;
    const unsigned short* ap = Ab + (gm0 + wave * 32 + r) * 2048L + cg;
    const unsigned short* bp = Bb + (gn0 + wave * 32 + r) * 8192L + cg;
    unsigned short* asl = &As[wave * 2048];
    unsigned short* bsl = &Bs[wave * 2048];

    const int wm   = (wave & 1) * 64;
    const int wn   = (wave >> 1) * 64;
    const int fr   = lane & 15;
    const int quad = lane >> 4;
    const int sw   = fr & 7;

    f32x4 acc[4][4];
#pragma unroll
    for (int i = 0; i < 4; i++)
#pragma unroll
        for (int j = 0; j < 4; j++) acc[i][j] = f32x4{0.f, 0.f, 0.f, 0.f};

    for (int k0 = 0; k0 < 2048; k0 += 64) {
        GLDS16(ap, asl);
        GLDS16(ap + 8 * 2048L, asl + 512);
        GLDS16(ap + 16 * 2048L, asl + 1024);
        GLDS16(ap + 24 * 2048L, asl + 1536);
        GLDS16(bp, bsl);
        GLDS16(bp + 8 * 8192L, bsl + 512);
        GLDS16(bp + 16 * 8192L, bsl + 1024);
        GLDS16(bp + 24 * 8192L, bsl + 1536);
        ap += 64;
        bp += 64;
        __syncthreads();

#pragma unroll
        for (int t = 0; t < 2; t++) {
            const int qs = ((t * 4 + quad) ^ sw) * 8;
            bf16x8 af[4], bf[4];
#pragma unroll
            for (int i = 0; i < 4; i++)
                af[i] = *(const bf16x8*)&As[(wm + i * 16 + fr) * 64 + qs];
#pragma unroll
            for (int j = 0; j < 4; j++)
                bf[j] = *(const bf16x8*)&Bs[(wn + j * 16 + fr) * 64 + qs];
#pragma unroll
            for (int i = 0; i < 4; i++)
#pragma unroll
                for (int j = 0; j < 4; j++)
                    acc[i][j] = __builtin_amdgcn_mfma_f32_16x16x32_bf16(
                        af[i], bf[j], acc[i][j], 0, 0, 0);
        }
        __syncthreads();
    }

    float* Ob = out + (long)bz * 2048 * 1024;
    const float* lb = l + (long)bz * 2048;
    const long crow0 = gm0 + wm + quad * 4;
#pragma unroll
    for (int i = 0; i < 4; i++) {
        const long rb = crow0 + i * 16;
        float inv[4];
#pragma unroll
        for (int rr = 0; rr < 4; rr++) inv[rr] = 1.0f / lb[rb + rr];
#pragma unroll
        for (int j = 0; j < 4; j++) {
            const long cb = gn0 + wn + j * 16 + fr;
#pragma unroll
            for (int rr = 0; rr < 4; rr++)
                Ob[(rb + rr) * 1024L + cb] = acc[i][j][rr] * inv[rr];
        }
    }
}

// Fused prep: [0,8192) convert x; [8192,8192+3072) transpose weights;
// block 11264 zeroes l (8192 floats).
__global__ __launch_bounds__(256) void prep(
    const float* __restrict__ x,
    const float* __restrict__ Wq, const float* __restrict__ Wk,
    const float* __restrict__ Wv,
    unsigned short* __restrict__ xb, unsigned short* __restrict__ Wqkvt,
    float* __restrict__ l)
{
    __shared__ float t[32][33];
    const int b = blockIdx.x;
    const int tid = threadIdx.x;
    if (b < 8192) {
        int i = b * 256 + tid;
        float4 v = ((const float4*)x)[i];
        ushort4 o;
        o.x = f2bf(v.x); o.y = f2bf(v.y); o.z = f2bf(v.z); o.w = f2bf(v.w);
        ((ushort4*)xb)[i] = o;
        return;
    }
    if (b == 8192 + 3072) {
        float4 z = {0.f, 0.f, 0.f, 0.f};
#pragma unroll
        for (int i = 0; i < 8; i++)
            ((float4*)l)[tid * 8 + i] = z;
        return;
    }
    int tix = b - 8192;
    const int w = tix >> 10;
    tix &= 1023;
    const float* W = (w == 0) ? Wq : (w == 1) ? Wk : Wv;
    unsigned short* Wt = Wqkvt + (long)w * 1024 * 1024;
    const int bx = (tix & 31) * 32;
    const int by = (tix >> 5) * 32;
    const int tx = tid & 31;
    const int ty = (tid >> 5) * 4;
#pragma unroll
    for (int j = 0; j < 4; j++)
        t[ty + j][tx] = W[(long)(by + ty + j) * 1024 + bx + tx];
    __syncthreads();
#pragma unroll
    for (int j = 0; j < 4; j++)
        Wt[(long)(bx + ty + j) * 1024 + by + tx] = f2bf(t[tx][ty + j]);
}

extern "C" void kernel_launch(void* const* d_in, const int* in_sizes, int n_in,
                              void* d_out, int out_size, void* d_ws,
                              size_t ws_size, hipStream_t stream)
{
    const float* x  = (const float*)d_in[0];
    const float* Wq = (const float*)d_in[1];
    const float* Wk = (const float*)d_in[2];
    const float* Wv = (const float*)d_in[3];
    float* out = (float*)d_out;

    const long M1 = 1024 * 1024;
    unsigned short* u     = (unsigned short*)d_ws;
    unsigned short* xb    = u;                  // 8M
    unsigned short* Wqkvt = u + 8 * M1;         // 3M
    unsigned short* QKb   = Wqkvt + 3 * M1;     // 16M [8192 x 2048]
    unsigned short* Vtb   = QKb + 16 * M1;      // 8M  [1024 x 8192]
    unsigned short* Pb    = Vtb + 8 * M1;       // 16M [4 x 2048 x 2048]
    float* l              = (float*)(Pb + 16 * M1);  // 8192 f32

    dim3 blk(256);

    prep<<<dim3(8192 + 3072 + 1), blk, 0, stream>>>(x, Wq, Wk, Wv, xb, Wqkvt, l);

    // QKV fused: [8192x1024] @ [3072x1024]^T
    gemm_qkv<<<dim3(24, 64), blk, 0, stream>>>(xb, Wqkvt, QKb, Vtb);

    // P'[j,i] = exp((K_j.Q_i)/32) bf16, + row sums l
    gemm_scores<<<dim3(16, 16, 4), blk, 0, stream>>>(QKb, Pb, l);

    // out = (P' @ V) / l  (128x128 tiles)
    gemm_pv<<<dim3(8, 16, 4), blk, 0, stream>>>(Pb, Vtb, l, out);
}